// Round 1
// baseline (805.604 us; speedup 1.0000x reference)
//
#include <hip/hip_runtime.h>

typedef float floatx4 __attribute__((ext_vector_type(4)));
typedef __bf16 bf16x4 __attribute__((ext_vector_type(4)));
typedef __bf16 bf16x8 __attribute__((ext_vector_type(8)));

#define D_MODEL 1024
#define D_FF 4096
#define NE 8

// LDS tile: 128 rows x 32 k-elems (bf16), stored as 64B rows with XOR-swizzled
// 16B granules: elem (row,k) -> row*32 + (((k>>3) ^ ((row>>2)&3))<<3) + (k&7)
__device__ __forceinline__ int lds_off(int row, int k) {
    return row * 32 + ((((k >> 3) ^ ((row >> 2) & 3)) << 3) | (k & 7));
}

// ---------------- router: logits, softmax-top2, renorm, build expert lists ---
__global__ __launch_bounds__(256) void router_kernel(
    const float* __restrict__ x, const float* __restrict__ Wr,
    const float* __restrict__ br, int* __restrict__ cnt,
    int* __restrict__ list, float* __restrict__ w_slot, int T)
{
    int wv = threadIdx.x >> 6;
    int lane = threadIdx.x & 63;
    int t = blockIdx.x * 4 + wv;
    if (t >= T) return;

    const float* xp = x + (size_t)t * D_MODEL;
    float acc[8] = {0.f,0.f,0.f,0.f,0.f,0.f,0.f,0.f};
#pragma unroll
    for (int i = 0; i < 16; ++i) {
        int d = i * 64 + lane;
        float xv = xp[d];
        float4 w0 = *(const float4*)(Wr + d * 8);
        float4 w1 = *(const float4*)(Wr + d * 8 + 4);
        acc[0] += xv * w0.x; acc[1] += xv * w0.y;
        acc[2] += xv * w0.z; acc[3] += xv * w0.w;
        acc[4] += xv * w1.x; acc[5] += xv * w1.y;
        acc[6] += xv * w1.z; acc[7] += xv * w1.w;
    }
#pragma unroll
    for (int off = 32; off >= 1; off >>= 1) {
#pragma unroll
        for (int e = 0; e < 8; ++e)
            acc[e] += __shfl_down(acc[e], off, 64);
    }
    if (lane == 0) {
        float l[8];
#pragma unroll
        for (int e = 0; e < 8; ++e) l[e] = acc[e] + br[e];
        // top-2, ties -> lower index (matches lax.top_k)
        int i0 = 0; float v0 = l[0];
#pragma unroll
        for (int e = 1; e < 8; ++e) if (l[e] > v0) { v0 = l[e]; i0 = e; }
        int i1 = -1; float v1 = -3.4e38f;
#pragma unroll
        for (int e = 0; e < 8; ++e) if (e != i0 && l[e] > v1) { v1 = l[e]; i1 = e; }
        float ex = __expf(v1 - v0);         // <= 1
        float w0 = 1.f / (1.f + ex);
        float w1 = ex / (1.f + ex);
        int p0 = atomicAdd(&cnt[i0], 1);
        list[i0 * T + p0] = 2 * t;
        int p1 = atomicAdd(&cnt[i1], 1);
        list[i1 * T + p1] = 2 * t + 1;
        w_slot[2 * t]     = w0;
        w_slot[2 * t + 1] = w1;
    }
}

// ---------------- gate+up GEMM (bf16 MFMA) + SwiGLU -> H (bf16) --------------
__global__ __launch_bounds__(256, 2) void gateup_kernel(
    const float* __restrict__ x, const float* __restrict__ Wg,
    const float* __restrict__ bg, const float* __restrict__ Wu,
    const float* __restrict__ bu, const int* __restrict__ cnt,
    const int* __restrict__ list, unsigned short* __restrict__ Hraw, int T)
{
    const int e  = blockIdx.z;
    const int m0 = blockIdx.y * 128;
    const int n0 = blockIdx.x * 128;
    const int count = cnt[e];
    if (m0 >= count) return;

    __bf16* H = (__bf16*)Hraw;
    __shared__ __bf16 ldsA[4096];
    __shared__ __bf16 ldsBg[4096];
    __shared__ __bf16 ldsBu[4096];
    __shared__ int s_entry[128];

    const int tid = threadIdx.x;
    if (tid < 128) {
        int r = m0 + tid;
        s_entry[tid] = (r < count) ? list[e * T + r] : list[e * T];
    }
    __syncthreads();

    // precompute A staging sources (4 groups of 4 floats per thread)
    const float* aptr[4];
    int awoff[4];
#pragma unroll
    for (int it = 0; it < 4; ++it) {
        int g = it * 256 + tid;
        int m = g >> 3, kg = g & 7;
        int token = s_entry[m] >> 1;
        aptr[it] = x + (size_t)token * D_MODEL + kg * 4;
        awoff[it] = lds_off(m, kg * 4);
    }
    // B staging: 4x4 micro-tile transpose
    const int kgrp = tid >> 5;      // 0..7 (k sub-group of 4)
    const int fg   = tid & 31;      // f group of 4
    const float* gbase = Wg + (size_t)e * D_MODEL * D_FF + (size_t)(kgrp * 4) * D_FF + n0 + fg * 4;
    const float* ubase = Wu + (size_t)e * D_MODEL * D_FF + (size_t)(kgrp * 4) * D_FF + n0 + fg * 4;
    int bwoff[4];
#pragma unroll
    for (int i = 0; i < 4; ++i) bwoff[i] = lds_off(fg * 4 + i, kgrp * 4);

    const int wv = tid >> 6, lane = tid & 63;
    const int wm = wv >> 1, wn = wv & 1;
    const int q = lane >> 4, ln = lane & 15;
    int aoff[4], boff[4];
#pragma unroll
    for (int i = 0; i < 4; ++i) {
        aoff[i] = lds_off(wm * 64 + i * 16 + ln, q * 8);
        boff[i] = lds_off(wn * 64 + i * 16 + ln, q * 8);
    }

    floatx4 accg[4][4] = {};
    floatx4 accu[4][4] = {};

    for (int k0 = 0; k0 < D_MODEL; k0 += 32) {
        // stage A (gathered X rows, fp32 -> bf16)
#pragma unroll
        for (int it = 0; it < 4; ++it) {
            float4 v = *(const float4*)(aptr[it] + k0);
            bf16x4 p = {(__bf16)v.x, (__bf16)v.y, (__bf16)v.z, (__bf16)v.w};
            *(bf16x4*)&ldsA[awoff[it]] = p;
        }
        // stage Bg transposed
        {
            const float* b = gbase + (size_t)k0 * D_FF;
            float4 r0 = *(const float4*)(b);
            float4 r1 = *(const float4*)(b + D_FF);
            float4 r2 = *(const float4*)(b + 2 * D_FF);
            float4 r3 = *(const float4*)(b + 3 * D_FF);
            bf16x4 p0 = {(__bf16)r0.x, (__bf16)r1.x, (__bf16)r2.x, (__bf16)r3.x};
            bf16x4 p1 = {(__bf16)r0.y, (__bf16)r1.y, (__bf16)r2.y, (__bf16)r3.y};
            bf16x4 p2 = {(__bf16)r0.z, (__bf16)r1.z, (__bf16)r2.z, (__bf16)r3.z};
            bf16x4 p3 = {(__bf16)r0.w, (__bf16)r1.w, (__bf16)r2.w, (__bf16)r3.w};
            *(bf16x4*)&ldsBg[bwoff[0]] = p0;
            *(bf16x4*)&ldsBg[bwoff[1]] = p1;
            *(bf16x4*)&ldsBg[bwoff[2]] = p2;
            *(bf16x4*)&ldsBg[bwoff[3]] = p3;
        }
        // stage Bu transposed
        {
            const float* b = ubase + (size_t)k0 * D_FF;
            float4 r0 = *(const float4*)(b);
            float4 r1 = *(const float4*)(b + D_FF);
            float4 r2 = *(const float4*)(b + 2 * D_FF);
            float4 r3 = *(const float4*)(b + 3 * D_FF);
            bf16x4 p0 = {(__bf16)r0.x, (__bf16)r1.x, (__bf16)r2.x, (__bf16)r3.x};
            bf16x4 p1 = {(__bf16)r0.y, (__bf16)r1.y, (__bf16)r2.y, (__bf16)r3.y};
            bf16x4 p2 = {(__bf16)r0.z, (__bf16)r1.z, (__bf16)r2.z, (__bf16)r3.z};
            bf16x4 p3 = {(__bf16)r0.w, (__bf16)r1.w, (__bf16)r2.w, (__bf16)r3.w};
            *(bf16x4*)&ldsBu[bwoff[0]] = p0;
            *(bf16x4*)&ldsBu[bwoff[1]] = p1;
            *(bf16x4*)&ldsBu[bwoff[2]] = p2;
            *(bf16x4*)&ldsBu[bwoff[3]] = p3;
        }
        __syncthreads();

        bf16x8 af[4], bgf[4], buf[4];
#pragma unroll
        for (int i = 0; i < 4; ++i) af[i] = *(const bf16x8*)&ldsA[aoff[i]];
#pragma unroll
        for (int i = 0; i < 4; ++i) bgf[i] = *(const bf16x8*)&ldsBg[boff[i]];
#pragma unroll
        for (int i = 0; i < 4; ++i) buf[i] = *(const bf16x8*)&ldsBu[boff[i]];
#pragma unroll
        for (int mi = 0; mi < 4; ++mi)
#pragma unroll
            for (int ni = 0; ni < 4; ++ni) {
                accg[mi][ni] = __builtin_amdgcn_mfma_f32_16x16x32_bf16(af[mi], bgf[ni], accg[mi][ni], 0, 0, 0);
                accu[mi][ni] = __builtin_amdgcn_mfma_f32_16x16x32_bf16(af[mi], buf[ni], accu[mi][ni], 0, 0, 0);
            }
        __syncthreads();
    }

    // epilogue: SwiGLU, write H rows (row id = entry = 2t+slot)
#pragma unroll
    for (int ni = 0; ni < 4; ++ni) {
        int col = n0 + wn * 64 + ni * 16 + ln;
        float bgv = bg[e * D_FF + col];
        float buv = bu[e * D_FF + col];
#pragma unroll
        for (int mi = 0; mi < 4; ++mi) {
            int lrow0 = wm * 64 + mi * 16 + q * 4;
#pragma unroll
            for (int r = 0; r < 4; ++r) {
                int lr = lrow0 + r;
                if (m0 + lr < count) {
                    int entry = s_entry[lr];
                    float g = accg[mi][ni][r] + bgv;
                    float u = accu[mi][ni][r] + buv;
                    float h = g / (1.f + __expf(-g)) * u;
                    H[(size_t)entry * D_FF + col] = (__bf16)h;
                }
            }
        }
    }
}

// ---------------- down GEMM (H @ Wd) + weighted scatter-add ------------------
__global__ __launch_bounds__(256, 2) void down_kernel(
    const unsigned short* __restrict__ Hraw, const float* __restrict__ Wd,
    const float* __restrict__ bd, const int* __restrict__ cnt,
    const int* __restrict__ list, const float* __restrict__ w_slot,
    float* __restrict__ out, int T)
{
    const int e  = blockIdx.z;
    const int m0 = blockIdx.y * 128;
    const int n0 = blockIdx.x * 128;
    const int count = cnt[e];
    if (m0 >= count) return;

    const __bf16* H = (const __bf16*)Hraw;
    __shared__ __bf16 ldsA[4096];
    __shared__ __bf16 ldsB[4096];
    __shared__ int s_entry[128];

    const int tid = threadIdx.x;
    if (tid < 128) {
        int r = m0 + tid;
        s_entry[tid] = (r < count) ? list[e * T + r] : list[e * T];
    }
    __syncthreads();

    // A staging: 2 groups of 8 bf16 per thread
    const __bf16* aptr[2];
    int awoff[2];
#pragma unroll
    for (int it = 0; it < 2; ++it) {
        int g = it * 256 + tid;
        int m = g >> 2, k16 = g & 3;
        aptr[it] = H + (size_t)s_entry[m] * D_FF + k16 * 8;
        awoff[it] = lds_off(m, k16 * 8);
    }
    const int kgrp = tid >> 5;
    const int fg   = tid & 31;
    const float* dbase = Wd + (size_t)e * D_FF * D_MODEL + (size_t)(kgrp * 4) * D_MODEL + n0 + fg * 4;
    int bwoff[4];
#pragma unroll
    for (int i = 0; i < 4; ++i) bwoff[i] = lds_off(fg * 4 + i, kgrp * 4);

    const int wv = tid >> 6, lane = tid & 63;
    const int wm = wv >> 1, wn = wv & 1;
    const int q = lane >> 4, ln = lane & 15;
    int aoff[4], boff[4];
#pragma unroll
    for (int i = 0; i < 4; ++i) {
        aoff[i] = lds_off(wm * 64 + i * 16 + ln, q * 8);
        boff[i] = lds_off(wn * 64 + i * 16 + ln, q * 8);
    }

    floatx4 acc[4][4] = {};

    for (int k0 = 0; k0 < D_FF; k0 += 32) {
#pragma unroll
        for (int it = 0; it < 2; ++it) {
            bf16x8 v = *(const bf16x8*)(aptr[it] + k0);
            *(bf16x8*)&ldsA[awoff[it]] = v;
        }
        {
            const float* b = dbase + (size_t)k0 * D_MODEL;
            float4 r0 = *(const float4*)(b);
            float4 r1 = *(const float4*)(b + D_MODEL);
            float4 r2 = *(const float4*)(b + 2 * D_MODEL);
            float4 r3 = *(const float4*)(b + 3 * D_MODEL);
            bf16x4 p0 = {(__bf16)r0.x, (__bf16)r1.x, (__bf16)r2.x, (__bf16)r3.x};
            bf16x4 p1 = {(__bf16)r0.y, (__bf16)r1.y, (__bf16)r2.y, (__bf16)r3.y};
            bf16x4 p2 = {(__bf16)r0.z, (__bf16)r1.z, (__bf16)r2.z, (__bf16)r3.z};
            bf16x4 p3 = {(__bf16)r0.w, (__bf16)r1.w, (__bf16)r2.w, (__bf16)r3.w};
            *(bf16x4*)&ldsB[bwoff[0]] = p0;
            *(bf16x4*)&ldsB[bwoff[1]] = p1;
            *(bf16x4*)&ldsB[bwoff[2]] = p2;
            *(bf16x4*)&ldsB[bwoff[3]] = p3;
        }
        __syncthreads();

        bf16x8 af[4], bf[4];
#pragma unroll
        for (int i = 0; i < 4; ++i) af[i] = *(const bf16x8*)&ldsA[aoff[i]];
#pragma unroll
        for (int i = 0; i < 4; ++i) bf[i] = *(const bf16x8*)&ldsB[boff[i]];
#pragma unroll
        for (int mi = 0; mi < 4; ++mi)
#pragma unroll
            for (int ni = 0; ni < 4; ++ni)
                acc[mi][ni] = __builtin_amdgcn_mfma_f32_16x16x32_bf16(af[mi], bf[ni], acc[mi][ni], 0, 0, 0);
        __syncthreads();
    }

#pragma unroll
    for (int ni = 0; ni < 4; ++ni) {
        int col = n0 + wn * 64 + ni * 16 + ln;
        float bdv = bd[e * D_MODEL + col];
#pragma unroll
        for (int mi = 0; mi < 4; ++mi) {
            int lrow0 = wm * 64 + mi * 16 + q * 4;
#pragma unroll
            for (int r = 0; r < 4; ++r) {
                int lr = lrow0 + r;
                if (m0 + lr < count) {
                    int entry = s_entry[lr];
                    int token = entry >> 1;
                    float w = w_slot[entry];
                    atomicAdd(&out[(size_t)token * D_MODEL + col],
                              w * (acc[mi][ni][r] + bdv));
                }
            }
        }
    }
}

extern "C" void kernel_launch(void* const* d_in, const int* in_sizes, int n_in,
                              void* d_out, int out_size, void* d_ws, size_t ws_size,
                              hipStream_t stream) {
    const float* x  = (const float*)d_in[0];
    const float* Wr = (const float*)d_in[1];
    const float* br = (const float*)d_in[2];
    const float* Wg = (const float*)d_in[3];
    const float* bg = (const float*)d_in[4];
    const float* Wu = (const float*)d_in[5];
    const float* bu = (const float*)d_in[6];
    const float* Wd = (const float*)d_in[7];
    const float* bd = (const float*)d_in[8];
    float* out = (float*)d_out;
    const int T = in_sizes[0] / D_MODEL;   // 2048

    char* ws = (char*)d_ws;
    int*   cnt    = (int*)ws;
    int*   list   = (int*)(ws + 256);
    float* w_slot = (float*)(ws + 256 + (size_t)NE * T * 4);
    size_t hoff = 256 + (size_t)NE * T * 4 + (size_t)2 * T * 4;
    hoff = (hoff + 1023) & ~(size_t)1023;
    unsigned short* H = (unsigned short*)(ws + hoff);  // 2T x D_FF bf16 = 32 MB

    hipMemsetAsync(cnt, 0, 256, stream);
    hipMemsetAsync(out, 0, (size_t)T * D_MODEL * sizeof(float), stream);

    router_kernel<<<dim3((T + 3) / 4), dim3(256), 0, stream>>>(x, Wr, br, cnt, list, w_slot, T);

    dim3 gb(D_FF / 128, (T + 127) / 128, NE);
    gateup_kernel<<<gb, dim3(256), 0, stream>>>(x, Wg, bg, Wu, bu, cnt, list, H, T);

    dim3 gc(D_MODEL / 128, (T + 127) / 128, NE);
    down_kernel<<<gc, dim3(256), 0, stream>>>(H, Wd, bd, cnt, list, w_slot, out, T);
}

// Round 2
// 742.124 us; speedup vs baseline: 1.0855x; 1.0855x over previous
//
#include <hip/hip_runtime.h>

typedef float floatx4 __attribute__((ext_vector_type(4)));
typedef __bf16 bf16x4 __attribute__((ext_vector_type(4)));
typedef __bf16 bf16x8 __attribute__((ext_vector_type(8)));

#define D_MODEL 1024
#define D_FF 4096
#define NE 8

// ---- async global->LDS, 16B per lane. LDS dest must be lane-linear. ----
__device__ __forceinline__ void gload16(const void* g, void* l) {
    __builtin_amdgcn_global_load_lds(
        (const __attribute__((address_space(1))) void*)g,
        (__attribute__((address_space(3))) void*)l, 16, 0, 0);
}

// Swizzled tile: 128 rows x 32 k (bf16). Granule (16B = 8 elems) for (row, q)
// lives at element offset row*32 + ((q ^ ((row>>2)&3))<<3).  2-way max aliasing.
__device__ __forceinline__ int frag_off(int row, int q) {
    return row * 32 + ((q ^ ((row >> 2) & 3)) << 3);
}

// round-0 swizzle helper (fallback kernels)
__device__ __forceinline__ int lds_off(int row, int k) {
    return row * 32 + ((((k >> 3) ^ ((row >> 2) & 3)) << 3) | (k & 7));
}

// ---------------- router ----------------------------------------------------
__global__ __launch_bounds__(256) void router_kernel(
    const float* __restrict__ x, const float* __restrict__ Wr,
    const float* __restrict__ br, int* __restrict__ cnt,
    int* __restrict__ list, float* __restrict__ w_slot, int T)
{
    int wv = threadIdx.x >> 6;
    int lane = threadIdx.x & 63;
    int t = blockIdx.x * 4 + wv;
    if (t >= T) return;

    const float* xp = x + (size_t)t * D_MODEL;
    float acc[8] = {0.f,0.f,0.f,0.f,0.f,0.f,0.f,0.f};
#pragma unroll
    for (int i = 0; i < 16; ++i) {
        int d = i * 64 + lane;
        float xv = xp[d];
        float4 w0 = *(const float4*)(Wr + d * 8);
        float4 w1 = *(const float4*)(Wr + d * 8 + 4);
        acc[0] += xv * w0.x; acc[1] += xv * w0.y;
        acc[2] += xv * w0.z; acc[3] += xv * w0.w;
        acc[4] += xv * w1.x; acc[5] += xv * w1.y;
        acc[6] += xv * w1.z; acc[7] += xv * w1.w;
    }
#pragma unroll
    for (int off = 32; off >= 1; off >>= 1) {
#pragma unroll
        for (int e = 0; e < 8; ++e)
            acc[e] += __shfl_down(acc[e], off, 64);
    }
    if (lane == 0) {
        float l[8];
#pragma unroll
        for (int e = 0; e < 8; ++e) l[e] = acc[e] + br[e];
        int i0 = 0; float v0 = l[0];
#pragma unroll
        for (int e = 1; e < 8; ++e) if (l[e] > v0) { v0 = l[e]; i0 = e; }
        int i1 = -1; float v1 = -3.4e38f;
#pragma unroll
        for (int e = 0; e < 8; ++e) if (e != i0 && l[e] > v1) { v1 = l[e]; i1 = e; }
        float ex = __expf(v1 - v0);
        float w0 = 1.f / (1.f + ex);
        float w1 = ex / (1.f + ex);
        int p0 = atomicAdd(&cnt[i0], 1);
        list[i0 * T + p0] = 2 * t;
        int p1 = atomicAdd(&cnt[i1], 1);
        list[i1 * T + p1] = 2 * t + 1;
        w_slot[2 * t]     = w0;
        w_slot[2 * t + 1] = w1;
    }
}

// ---------------- x fp32 -> bf16 --------------------------------------------
__global__ __launch_bounds__(256) void xconv_kernel(
    const float* __restrict__ x, __bf16* __restrict__ Xb, int n4)
{
    int i = blockIdx.x * 256 + threadIdx.x;
    if (i < n4) {
        float4 v = ((const float4*)x)[i];
        bf16x4 o = {(__bf16)v.x, (__bf16)v.y, (__bf16)v.z, (__bf16)v.w};
        ((bf16x4*)Xb)[i] = o;
    }
}

// ---------------- W [E][K][N] fp32 -> Wt [E][N][K] bf16 ---------------------
__global__ __launch_bounds__(256) void tconv_kernel(
    const float* __restrict__ src, __bf16* __restrict__ dst, int K, int N)
{
    __shared__ float tile[64][65];
    const int kb = blockIdx.x * 64;
    const int nb = blockIdx.y * 64;
    const int e  = blockIdx.z;
    src += (size_t)e * K * N;
    dst += (size_t)e * K * N;
    const int tid = threadIdx.x;
    const int kr = tid >> 4;
    const int nc = (tid & 15) * 4;
#pragma unroll
    for (int i = 0; i < 4; ++i) {
        float4 v = *(const float4*)(src + (size_t)(kb + kr + i * 16) * N + nb + nc);
        tile[kr + i * 16][nc]     = v.x;
        tile[kr + i * 16][nc + 1] = v.y;
        tile[kr + i * 16][nc + 2] = v.z;
        tile[kr + i * 16][nc + 3] = v.w;
    }
    __syncthreads();
#pragma unroll
    for (int i = 0; i < 2; ++i) {
        int p = i * 256 + tid;
        int n = p >> 3;
        int jg = (p & 7) * 8;
        bf16x8 o;
#pragma unroll
        for (int j = 0; j < 8; ++j) o[j] = (__bf16)tile[jg + j][n];
        *(bf16x8*)(dst + (size_t)(nb + n) * K + kb + jg) = o;
    }
}

// ---------------- gate+up GEMM, m97-style ----------------------------------
__global__ __launch_bounds__(256, 2) void gateup2_kernel(
    const __bf16* __restrict__ Xb, const __bf16* __restrict__ Wgt,
    const __bf16* __restrict__ Wut, const float* __restrict__ bg,
    const float* __restrict__ bu, const int* __restrict__ cnt,
    const int* __restrict__ list, __bf16* __restrict__ H, int T)
{
    const int e  = blockIdx.z;
    const int m0 = blockIdx.y * 128;
    const int n0 = blockIdx.x * 128;
    const int count = cnt[e];
    if (m0 >= count) return;

    __shared__ __bf16 ldsA[4096];
    __shared__ __bf16 ldsBg[4096];
    __shared__ __bf16 ldsBu[4096];
    __shared__ int s_entry[128];

    const int tid = threadIdx.x;
    if (tid < 128) {
        int r = m0 + tid;
        s_entry[tid] = (r < count) ? list[e * T + r] : list[e * T];
    }
    __syncthreads();

    // granule p in {tid, tid+256}: row=p>>2, stored slot j=p&3 holds source
    // k-granule g = j ^ ((row>>2)&3)
    const __bf16* asrc[2]; const __bf16* gsrc[2]; const __bf16* usrc[2];
    char* adst[2]; char* gdst[2]; char* udst[2];
#pragma unroll
    for (int i = 0; i < 2; ++i) {
        int p = i * 256 + tid;
        int row = p >> 2, j = p & 3;
        int g = j ^ ((row >> 2) & 3);
        int token = s_entry[row] >> 1;
        asrc[i] = Xb + (size_t)token * D_MODEL + g * 8;
        gsrc[i] = Wgt + ((size_t)e * D_FF + n0 + row) * D_MODEL + g * 8;
        usrc[i] = Wut + ((size_t)e * D_FF + n0 + row) * D_MODEL + g * 8;
        adst[i] = (char*)ldsA  + (size_t)p * 16;
        gdst[i] = (char*)ldsBg + (size_t)p * 16;
        udst[i] = (char*)ldsBu + (size_t)p * 16;
    }

    const int wv = tid >> 6, lane = tid & 63;
    const int wm = wv >> 1, wn = wv & 1;
    const int q = lane >> 4, ln = lane & 15;
    int aoff[4], boff[4];
#pragma unroll
    for (int i = 0; i < 4; ++i) {
        aoff[i] = frag_off(wm * 64 + i * 16 + ln, q);
        boff[i] = frag_off(wn * 64 + i * 16 + ln, q);
    }

    floatx4 accg[4][4] = {};
    floatx4 accu[4][4] = {};

    for (int k0 = 0; k0 < D_MODEL; k0 += 32) {
#pragma unroll
        for (int i = 0; i < 2; ++i) {
            gload16(asrc[i] + k0, adst[i]);
            gload16(gsrc[i] + k0, gdst[i]);
            gload16(usrc[i] + k0, udst[i]);
        }
        __syncthreads();

        bf16x8 af[4], bgf[4], buf[4];
#pragma unroll
        for (int i = 0; i < 4; ++i) af[i]  = *(const bf16x8*)&ldsA[aoff[i]];
#pragma unroll
        for (int i = 0; i < 4; ++i) bgf[i] = *(const bf16x8*)&ldsBg[boff[i]];
#pragma unroll
        for (int i = 0; i < 4; ++i) buf[i] = *(const bf16x8*)&ldsBu[boff[i]];
#pragma unroll
        for (int mi = 0; mi < 4; ++mi)
#pragma unroll
            for (int ni = 0; ni < 4; ++ni) {
                accg[mi][ni] = __builtin_amdgcn_mfma_f32_16x16x32_bf16(af[mi], bgf[ni], accg[mi][ni], 0, 0, 0);
                accu[mi][ni] = __builtin_amdgcn_mfma_f32_16x16x32_bf16(af[mi], buf[ni], accu[mi][ni], 0, 0, 0);
            }
        __syncthreads();
    }

#pragma unroll
    for (int ni = 0; ni < 4; ++ni) {
        int col = n0 + wn * 64 + ni * 16 + ln;
        float bgv = bg[e * D_FF + col];
        float buv = bu[e * D_FF + col];
#pragma unroll
        for (int mi = 0; mi < 4; ++mi) {
            int lrow0 = wm * 64 + mi * 16 + q * 4;
#pragma unroll
            for (int r = 0; r < 4; ++r) {
                int lr = lrow0 + r;
                if (m0 + lr < count) {
                    int entry = s_entry[lr];
                    float g = accg[mi][ni][r] + bgv;
                    float u = accu[mi][ni][r] + buv;
                    float h = g / (1.f + __expf(-g)) * u;
                    H[(size_t)entry * D_FF + col] = (__bf16)h;
                }
            }
        }
    }
}

// ---------------- down GEMM (K-split x2) + weighted scatter-add -------------
__global__ __launch_bounds__(256, 2) void down2_kernel(
    const __bf16* __restrict__ H, const __bf16* __restrict__ Wdt,
    const float* __restrict__ bd, const int* __restrict__ cnt,
    const int* __restrict__ list, const float* __restrict__ w_slot,
    float* __restrict__ out, int T)
{
    const int e  = blockIdx.z >> 1;
    const int kc = blockIdx.z & 1;
    const int m0 = blockIdx.y * 128;
    const int n0 = blockIdx.x * 128;
    const int count = cnt[e];
    if (m0 >= count) return;

    __shared__ __bf16 ldsA[4096];
    __shared__ __bf16 ldsB[4096];
    __shared__ int s_entry[128];

    const int tid = threadIdx.x;
    if (tid < 128) {
        int r = m0 + tid;
        s_entry[tid] = (r < count) ? list[e * T + r] : list[e * T];
    }
    __syncthreads();

    const int kbase = kc * (D_FF / 2);
    const __bf16* asrc[2]; const __bf16* bsrc[2];
    char* adst[2]; char* bdst[2];
#pragma unroll
    for (int i = 0; i < 2; ++i) {
        int p = i * 256 + tid;
        int row = p >> 2, j = p & 3;
        int g = j ^ ((row >> 2) & 3);
        asrc[i] = H + (size_t)s_entry[row] * D_FF + kbase + g * 8;
        bsrc[i] = Wdt + ((size_t)e * D_MODEL + n0 + row) * D_FF + kbase + g * 8;
        adst[i] = (char*)ldsA + (size_t)p * 16;
        bdst[i] = (char*)ldsB + (size_t)p * 16;
    }

    const int wv = tid >> 6, lane = tid & 63;
    const int wm = wv >> 1, wn = wv & 1;
    const int q = lane >> 4, ln = lane & 15;
    int aoff[4], boff[4];
#pragma unroll
    for (int i = 0; i < 4; ++i) {
        aoff[i] = frag_off(wm * 64 + i * 16 + ln, q);
        boff[i] = frag_off(wn * 64 + i * 16 + ln, q);
    }

    floatx4 acc[4][4] = {};

    for (int k0 = 0; k0 < D_FF / 2; k0 += 32) {
#pragma unroll
        for (int i = 0; i < 2; ++i) {
            gload16(asrc[i] + k0, adst[i]);
            gload16(bsrc[i] + k0, bdst[i]);
        }
        __syncthreads();

        bf16x8 af[4], bf[4];
#pragma unroll
        for (int i = 0; i < 4; ++i) af[i] = *(const bf16x8*)&ldsA[aoff[i]];
#pragma unroll
        for (int i = 0; i < 4; ++i) bf[i] = *(const bf16x8*)&ldsB[boff[i]];
#pragma unroll
        for (int mi = 0; mi < 4; ++mi)
#pragma unroll
            for (int ni = 0; ni < 4; ++ni)
                acc[mi][ni] = __builtin_amdgcn_mfma_f32_16x16x32_bf16(af[mi], bf[ni], acc[mi][ni], 0, 0, 0);
        __syncthreads();
    }

#pragma unroll
    for (int ni = 0; ni < 4; ++ni) {
        int col = n0 + wn * 64 + ni * 16 + ln;
        float bdv = (kc == 0) ? bd[e * D_MODEL + col] : 0.f;
#pragma unroll
        for (int mi = 0; mi < 4; ++mi) {
            int lrow0 = wm * 64 + mi * 16 + q * 4;
#pragma unroll
            for (int r = 0; r < 4; ++r) {
                int lr = lrow0 + r;
                if (m0 + lr < count) {
                    int entry = s_entry[lr];
                    int token = entry >> 1;
                    float w = w_slot[entry];
                    atomicAdd(&out[(size_t)token * D_MODEL + col],
                              w * (acc[mi][ni][r] + bdv));
                }
            }
        }
    }
}

// ======================= round-0 fallback kernels ===========================
__global__ __launch_bounds__(256, 2) void gateup_fb(
    const float* __restrict__ x, const float* __restrict__ Wg,
    const float* __restrict__ bg, const float* __restrict__ Wu,
    const float* __restrict__ bu, const int* __restrict__ cnt,
    const int* __restrict__ list, unsigned short* __restrict__ Hraw, int T)
{
    const int e  = blockIdx.z;
    const int m0 = blockIdx.y * 128;
    const int n0 = blockIdx.x * 128;
    const int count = cnt[e];
    if (m0 >= count) return;

    __bf16* H = (__bf16*)Hraw;
    __shared__ __bf16 ldsA[4096];
    __shared__ __bf16 ldsBg[4096];
    __shared__ __bf16 ldsBu[4096];
    __shared__ int s_entry[128];

    const int tid = threadIdx.x;
    if (tid < 128) {
        int r = m0 + tid;
        s_entry[tid] = (r < count) ? list[e * T + r] : list[e * T];
    }
    __syncthreads();

    const float* aptr[4];
    int awoff[4];
#pragma unroll
    for (int it = 0; it < 4; ++it) {
        int g = it * 256 + tid;
        int m = g >> 3, kg = g & 7;
        int token = s_entry[m] >> 1;
        aptr[it] = x + (size_t)token * D_MODEL + kg * 4;
        awoff[it] = lds_off(m, kg * 4);
    }
    const int kgrp = tid >> 5;
    const int fg   = tid & 31;
    const float* gbase = Wg + (size_t)e * D_MODEL * D_FF + (size_t)(kgrp * 4) * D_FF + n0 + fg * 4;
    const float* ubase = Wu + (size_t)e * D_MODEL * D_FF + (size_t)(kgrp * 4) * D_FF + n0 + fg * 4;
    int bwoff[4];
#pragma unroll
    for (int i = 0; i < 4; ++i) bwoff[i] = lds_off(fg * 4 + i, kgrp * 4);

    const int wv = tid >> 6, lane = tid & 63;
    const int wm = wv >> 1, wn = wv & 1;
    const int q = lane >> 4, ln = lane & 15;
    int aoff[4], boff[4];
#pragma unroll
    for (int i = 0; i < 4; ++i) {
        aoff[i] = lds_off(wm * 64 + i * 16 + ln, q * 8);
        boff[i] = lds_off(wn * 64 + i * 16 + ln, q * 8);
    }

    floatx4 accg[4][4] = {};
    floatx4 accu[4][4] = {};

    for (int k0 = 0; k0 < D_MODEL; k0 += 32) {
#pragma unroll
        for (int it = 0; it < 4; ++it) {
            float4 v = *(const float4*)(aptr[it] + k0);
            bf16x4 p = {(__bf16)v.x, (__bf16)v.y, (__bf16)v.z, (__bf16)v.w};
            *(bf16x4*)&ldsA[awoff[it]] = p;
        }
        {
            const float* b = gbase + (size_t)k0 * D_FF;
            float4 r0 = *(const float4*)(b);
            float4 r1 = *(const float4*)(b + D_FF);
            float4 r2 = *(const float4*)(b + 2 * D_FF);
            float4 r3 = *(const float4*)(b + 3 * D_FF);
            bf16x4 p0 = {(__bf16)r0.x, (__bf16)r1.x, (__bf16)r2.x, (__bf16)r3.x};
            bf16x4 p1 = {(__bf16)r0.y, (__bf16)r1.y, (__bf16)r2.y, (__bf16)r3.y};
            bf16x4 p2 = {(__bf16)r0.z, (__bf16)r1.z, (__bf16)r2.z, (__bf16)r3.z};
            bf16x4 p3 = {(__bf16)r0.w, (__bf16)r1.w, (__bf16)r2.w, (__bf16)r3.w};
            *(bf16x4*)&ldsBg[bwoff[0]] = p0;
            *(bf16x4*)&ldsBg[bwoff[1]] = p1;
            *(bf16x4*)&ldsBg[bwoff[2]] = p2;
            *(bf16x4*)&ldsBg[bwoff[3]] = p3;
        }
        {
            const float* b = ubase + (size_t)k0 * D_FF;
            float4 r0 = *(const float4*)(b);
            float4 r1 = *(const float4*)(b + D_FF);
            float4 r2 = *(const float4*)(b + 2 * D_FF);
            float4 r3 = *(const float4*)(b + 3 * D_FF);
            bf16x4 p0 = {(__bf16)r0.x, (__bf16)r1.x, (__bf16)r2.x, (__bf16)r3.x};
            bf16x4 p1 = {(__bf16)r0.y, (__bf16)r1.y, (__bf16)r2.y, (__bf16)r3.y};
            bf16x4 p2 = {(__bf16)r0.z, (__bf16)r1.z, (__bf16)r2.z, (__bf16)r3.z};
            bf16x4 p3 = {(__bf16)r0.w, (__bf16)r1.w, (__bf16)r2.w, (__bf16)r3.w};
            *(bf16x4*)&ldsBu[bwoff[0]] = p0;
            *(bf16x4*)&ldsBu[bwoff[1]] = p1;
            *(bf16x4*)&ldsBu[bwoff[2]] = p2;
            *(bf16x4*)&ldsBu[bwoff[3]] = p3;
        }
        __syncthreads();

        bf16x8 af[4], bgf[4], buf[4];
#pragma unroll
        for (int i = 0; i < 4; ++i) af[i] = *(const bf16x8*)&ldsA[aoff[i]];
#pragma unroll
        for (int i = 0; i < 4; ++i) bgf[i] = *(const bf16x8*)&ldsBg[boff[i]];
#pragma unroll
        for (int i = 0; i < 4; ++i) buf[i] = *(const bf16x8*)&ldsBu[boff[i]];
#pragma unroll
        for (int mi = 0; mi < 4; ++mi)
#pragma unroll
            for (int ni = 0; ni < 4; ++ni) {
                accg[mi][ni] = __builtin_amdgcn_mfma_f32_16x16x32_bf16(af[mi], bgf[ni], accg[mi][ni], 0, 0, 0);
                accu[mi][ni] = __builtin_amdgcn_mfma_f32_16x16x32_bf16(af[mi], buf[ni], accu[mi][ni], 0, 0, 0);
            }
        __syncthreads();
    }

#pragma unroll
    for (int ni = 0; ni < 4; ++ni) {
        int col = n0 + wn * 64 + ni * 16 + ln;
        float bgv = bg[e * D_FF + col];
        float buv = bu[e * D_FF + col];
#pragma unroll
        for (int mi = 0; mi < 4; ++mi) {
            int lrow0 = wm * 64 + mi * 16 + q * 4;
#pragma unroll
            for (int r = 0; r < 4; ++r) {
                int lr = lrow0 + r;
                if (m0 + lr < count) {
                    int entry = s_entry[lr];
                    float g = accg[mi][ni][r] + bgv;
                    float u = accu[mi][ni][r] + buv;
                    float h = g / (1.f + __expf(-g)) * u;
                    H[(size_t)entry * D_FF + col] = (__bf16)h;
                }
            }
        }
    }
}

__global__ __launch_bounds__(256, 2) void down_fb(
    const unsigned short* __restrict__ Hraw, const float* __restrict__ Wd,
    const float* __restrict__ bd, const int* __restrict__ cnt,
    const int* __restrict__ list, const float* __restrict__ w_slot,
    float* __restrict__ out, int T)
{
    const int e  = blockIdx.z;
    const int m0 = blockIdx.y * 128;
    const int n0 = blockIdx.x * 128;
    const int count = cnt[e];
    if (m0 >= count) return;

    const __bf16* H = (const __bf16*)Hraw;
    __shared__ __bf16 ldsA[4096];
    __shared__ __bf16 ldsB[4096];
    __shared__ int s_entry[128];

    const int tid = threadIdx.x;
    if (tid < 128) {
        int r = m0 + tid;
        s_entry[tid] = (r < count) ? list[e * T + r] : list[e * T];
    }
    __syncthreads();

    const __bf16* aptr[2];
    int awoff[2];
#pragma unroll
    for (int it = 0; it < 2; ++it) {
        int g = it * 256 + tid;
        int m = g >> 2, k16 = g & 3;
        aptr[it] = H + (size_t)s_entry[m] * D_FF + k16 * 8;
        awoff[it] = lds_off(m, k16 * 8);
    }
    const int kgrp = tid >> 5;
    const int fg   = tid & 31;
    const float* dbase = Wd + (size_t)e * D_FF * D_MODEL + (size_t)(kgrp * 4) * D_MODEL + n0 + fg * 4;
    int bwoff[4];
#pragma unroll
    for (int i = 0; i < 4; ++i) bwoff[i] = lds_off(fg * 4 + i, kgrp * 4);

    const int wv = tid >> 6, lane = tid & 63;
    const int wm = wv >> 1, wn = wv & 1;
    const int q = lane >> 4, ln = lane & 15;
    int aoff[4], boff[4];
#pragma unroll
    for (int i = 0; i < 4; ++i) {
        aoff[i] = lds_off(wm * 64 + i * 16 + ln, q * 8);
        boff[i] = lds_off(wn * 64 + i * 16 + ln, q * 8);
    }

    floatx4 acc[4][4] = {};

    for (int k0 = 0; k0 < D_FF; k0 += 32) {
#pragma unroll
        for (int it = 0; it < 2; ++it) {
            bf16x8 v = *(const bf16x8*)(aptr[it] + k0);
            *(bf16x8*)&ldsA[awoff[it]] = v;
        }
        {
            const float* b = dbase + (size_t)k0 * D_MODEL;
            float4 r0 = *(const float4*)(b);
            float4 r1 = *(const float4*)(b + D_MODEL);
            float4 r2 = *(const float4*)(b + 2 * D_MODEL);
            float4 r3 = *(const float4*)(b + 3 * D_MODEL);
            bf16x4 p0 = {(__bf16)r0.x, (__bf16)r1.x, (__bf16)r2.x, (__bf16)r3.x};
            bf16x4 p1 = {(__bf16)r0.y, (__bf16)r1.y, (__bf16)r2.y, (__bf16)r3.y};
            bf16x4 p2 = {(__bf16)r0.z, (__bf16)r1.z, (__bf16)r2.z, (__bf16)r3.z};
            bf16x4 p3 = {(__bf16)r0.w, (__bf16)r1.w, (__bf16)r2.w, (__bf16)r3.w};
            *(bf16x4*)&ldsB[bwoff[0]] = p0;
            *(bf16x4*)&ldsB[bwoff[1]] = p1;
            *(bf16x4*)&ldsB[bwoff[2]] = p2;
            *(bf16x4*)&ldsB[bwoff[3]] = p3;
        }
        __syncthreads();

        bf16x8 af[4], bf[4];
#pragma unroll
        for (int i = 0; i < 4; ++i) af[i] = *(const bf16x8*)&ldsA[aoff[i]];
#pragma unroll
        for (int i = 0; i < 4; ++i) bf[i] = *(const bf16x8*)&ldsB[boff[i]];
#pragma unroll
        for (int mi = 0; mi < 4; ++mi)
#pragma unroll
            for (int ni = 0; ni < 4; ++ni)
                acc[mi][ni] = __builtin_amdgcn_mfma_f32_16x16x32_bf16(af[mi], bf[ni], acc[mi][ni], 0, 0, 0);
        __syncthreads();
    }

#pragma unroll
    for (int ni = 0; ni < 4; ++ni) {
        int col = n0 + wn * 64 + ni * 16 + ln;
        float bdv = bd[e * D_MODEL + col];
#pragma unroll
        for (int mi = 0; mi < 4; ++mi) {
            int lrow0 = wm * 64 + mi * 16 + q * 4;
#pragma unroll
            for (int r = 0; r < 4; ++r) {
                int lr = lrow0 + r;
                if (m0 + lr < count) {
                    int entry = s_entry[lr];
                    int token = entry >> 1;
                    float w = w_slot[entry];
                    atomicAdd(&out[(size_t)token * D_MODEL + col],
                              w * (acc[mi][ni][r] + bdv));
                }
            }
        }
    }
}

// ============================================================================
extern "C" void kernel_launch(void* const* d_in, const int* in_sizes, int n_in,
                              void* d_out, int out_size, void* d_ws, size_t ws_size,
                              hipStream_t stream) {
    const float* x  = (const float*)d_in[0];
    const float* Wr = (const float*)d_in[1];
    const float* br = (const float*)d_in[2];
    const float* Wg = (const float*)d_in[3];
    const float* bg = (const float*)d_in[4];
    const float* Wu = (const float*)d_in[5];
    const float* bu = (const float*)d_in[6];
    const float* Wd = (const float*)d_in[7];
    const float* bd = (const float*)d_in[8];
    float* out = (float*)d_out;
    const int T = in_sizes[0] / D_MODEL;   // 2048

    char* ws = (char*)d_ws;
    size_t off = 256;
    int*   cnt    = (int*)ws;
    int*   list   = (int*)(ws + off);              off += (size_t)NE * T * 4;
    float* w_slot = (float*)(ws + off);            off += (size_t)2 * T * 4;
    off = (off + 1023) & ~(size_t)1023;
    __bf16* Xb  = (__bf16*)(ws + off);             off += (size_t)T * D_MODEL * 2;
    __bf16* H   = (__bf16*)(ws + off);             size_t h_at = off - (size_t)T * D_MODEL * 2;
    off += (size_t)2 * T * D_FF * 2;
    __bf16* Wgt = (__bf16*)(ws + off);             off += (size_t)NE * D_MODEL * D_FF * 2;
    __bf16* Wut = (__bf16*)(ws + off);             off += (size_t)NE * D_MODEL * D_FF * 2;
    __bf16* Wdt = (__bf16*)(ws + off);             off += (size_t)NE * D_FF * D_MODEL * 2;
    const bool big = (ws_size >= off);

    hipMemsetAsync(cnt, 0, 256, stream);
    hipMemsetAsync(out, 0, (size_t)T * D_MODEL * sizeof(float), stream);

    router_kernel<<<dim3((T + 3) / 4), dim3(256), 0, stream>>>(x, Wr, br, cnt, list, w_slot, T);

    if (big) {
        int n4 = T * D_MODEL / 4;
        xconv_kernel<<<dim3((n4 + 255) / 256), dim3(256), 0, stream>>>(x, Xb, n4);
        tconv_kernel<<<dim3(D_MODEL / 64, D_FF / 64, NE), dim3(256), 0, stream>>>(Wg, Wgt, D_MODEL, D_FF);
        tconv_kernel<<<dim3(D_MODEL / 64, D_FF / 64, NE), dim3(256), 0, stream>>>(Wu, Wut, D_MODEL, D_FF);
        tconv_kernel<<<dim3(D_FF / 64, D_MODEL / 64, NE), dim3(256), 0, stream>>>(Wd, Wdt, D_FF, D_MODEL);

        dim3 gb(D_FF / 128, (T + 127) / 128, NE);
        gateup2_kernel<<<gb, dim3(256), 0, stream>>>(Xb, Wgt, Wut, bg, bu, cnt, list, H, T);

        dim3 gc(D_MODEL / 128, (T + 127) / 128, NE * 2);
        down2_kernel<<<gc, dim3(256), 0, stream>>>(H, Wdt, bd, cnt, list, w_slot, out, T);
    } else {
        // round-0 path (fits in ~33 MB of workspace)
        unsigned short* Hf = (unsigned short*)(ws + ((h_at + 1023) & ~(size_t)1023) + 0);
        Hf = (unsigned short*)Xb;  // reuse first aligned region for H
        dim3 gb(D_FF / 128, (T + 127) / 128, NE);
        gateup_fb<<<gb, dim3(256), 0, stream>>>(x, Wg, bg, Wu, bu, cnt, list, Hf, T);
        dim3 gc(D_MODEL / 128, (T + 127) / 128, NE);
        down_fb<<<gc, dim3(256), 0, stream>>>((const unsigned short*)Hf, Wd, bd, cnt, list, w_slot, out, T);
    }
}

// Round 3
// 677.905 us; speedup vs baseline: 1.1884x; 1.0947x over previous
//
#include <hip/hip_runtime.h>

typedef float floatx4 __attribute__((ext_vector_type(4)));
typedef __bf16 bf16x4 __attribute__((ext_vector_type(4)));
typedef __bf16 bf16x8 __attribute__((ext_vector_type(8)));

#define D_MODEL 1024
#define D_FF 4096
#define NE 8

// ---- async global->LDS, 16B per lane. LDS dest must be lane-linear. ----
__device__ __forceinline__ void gload16(const void* g, void* l) {
    __builtin_amdgcn_global_load_lds(
        (const __attribute__((address_space(1))) void*)g,
        (__attribute__((address_space(3))) void*)l, 16, 0, 0);
}

// Swizzled tile: rows x 32 k (bf16). Granule (16B = 8 elems) for (row, q)
// lives at element offset row*32 + ((q ^ ((row>>2)&3))<<3).
__device__ __forceinline__ int frag_off(int row, int q) {
    return row * 32 + ((q ^ ((row >> 2) & 3)) << 3);
}

// ---------------- router ----------------------------------------------------
__global__ __launch_bounds__(256) void router_kernel(
    const float* __restrict__ x, const float* __restrict__ Wr,
    const float* __restrict__ br, int* __restrict__ cnt,
    int* __restrict__ list, float* __restrict__ w_slot, int T)
{
    int wv = threadIdx.x >> 6;
    int lane = threadIdx.x & 63;
    int t = blockIdx.x * 4 + wv;
    if (t >= T) return;

    const float* xp = x + (size_t)t * D_MODEL;
    float acc[8] = {0.f,0.f,0.f,0.f,0.f,0.f,0.f,0.f};
#pragma unroll
    for (int i = 0; i < 16; ++i) {
        int d = i * 64 + lane;
        float xv = xp[d];
        float4 w0 = *(const float4*)(Wr + d * 8);
        float4 w1 = *(const float4*)(Wr + d * 8 + 4);
        acc[0] += xv * w0.x; acc[1] += xv * w0.y;
        acc[2] += xv * w0.z; acc[3] += xv * w0.w;
        acc[4] += xv * w1.x; acc[5] += xv * w1.y;
        acc[6] += xv * w1.z; acc[7] += xv * w1.w;
    }
#pragma unroll
    for (int off = 32; off >= 1; off >>= 1) {
#pragma unroll
        for (int e = 0; e < 8; ++e)
            acc[e] += __shfl_down(acc[e], off, 64);
    }
    if (lane == 0) {
        float l[8];
#pragma unroll
        for (int e = 0; e < 8; ++e) l[e] = acc[e] + br[e];
        int i0 = 0; float v0 = l[0];
#pragma unroll
        for (int e = 1; e < 8; ++e) if (l[e] > v0) { v0 = l[e]; i0 = e; }
        int i1 = -1; float v1 = -3.4e38f;
#pragma unroll
        for (int e = 0; e < 8; ++e) if (e != i0 && l[e] > v1) { v1 = l[e]; i1 = e; }
        float ex = __expf(v1 - v0);
        float w0 = 1.f / (1.f + ex);
        float w1 = ex / (1.f + ex);
        int p0 = atomicAdd(&cnt[i0], 1);
        list[i0 * T + p0] = 2 * t;
        int p1 = atomicAdd(&cnt[i1], 1);
        list[i1 * T + p1] = 2 * t + 1;
        w_slot[2 * t]     = w0;
        w_slot[2 * t + 1] = w1;
    }
}

// ---------------- fused prep: 3x transpose-convert + x convert ---------------
// blocks [0,8192): Wg, [8192,16384): Wu, [16384,24576): Wd, [24576,25600): x
__global__ __launch_bounds__(256) void prep_kernel(
    const float* __restrict__ Wg, const float* __restrict__ Wu,
    const float* __restrict__ Wd, const float* __restrict__ x,
    __bf16* __restrict__ Wgt, __bf16* __restrict__ Wut,
    __bf16* __restrict__ Wdt, __bf16* __restrict__ Xb)
{
    const int bid = blockIdx.x;
    const int tid = threadIdx.x;
    if (bid >= 24576) {
        int base = (bid - 24576) * 2048 + tid * 8;
        float4 v0 = *(const float4*)(x + base);
        float4 v1 = *(const float4*)(x + base + 4);
        bf16x8 o = {(__bf16)v0.x, (__bf16)v0.y, (__bf16)v0.z, (__bf16)v0.w,
                    (__bf16)v1.x, (__bf16)v1.y, (__bf16)v1.z, (__bf16)v1.w};
        *(bf16x8*)(Xb + base) = o;
        return;
    }
    const int tensor = bid >> 13;
    const int rem = bid & 8191;
    const int e = rem >> 10;
    const int tile = rem & 1023;
    const float* src; __bf16* dst; int K, N, kb, nb;
    if (tensor == 0)      { src = Wg; dst = Wgt; }
    else if (tensor == 1) { src = Wu; dst = Wut; }
    else                  { src = Wd; dst = Wdt; }
    if (tensor < 2) { K = 1024; N = 4096; kb = (tile & 15) << 6; nb = (tile >> 4) << 6; }
    else            { K = 4096; N = 1024; kb = (tile & 63) << 6; nb = (tile >> 6) << 6; }
    src += (size_t)e * K * N;
    dst += (size_t)e * K * N;

    __shared__ __bf16 tileT[64 * 72];   // [n][k], stride 72 (144B, 16B-aligned)
    const int kr = (tid >> 4) << 2;     // 4 consecutive k rows
    const int nc = (tid & 15) << 2;     // 4 consecutive n cols
    const float* s0 = src + (size_t)(kb + kr) * N + nb + nc;
    float4 r0 = *(const float4*)(s0);
    float4 r1 = *(const float4*)(s0 + N);
    float4 r2 = *(const float4*)(s0 + 2 * N);
    float4 r3 = *(const float4*)(s0 + 3 * N);
    bf16x4 c0 = {(__bf16)r0.x, (__bf16)r1.x, (__bf16)r2.x, (__bf16)r3.x};
    bf16x4 c1 = {(__bf16)r0.y, (__bf16)r1.y, (__bf16)r2.y, (__bf16)r3.y};
    bf16x4 c2 = {(__bf16)r0.z, (__bf16)r1.z, (__bf16)r2.z, (__bf16)r3.z};
    bf16x4 c3 = {(__bf16)r0.w, (__bf16)r1.w, (__bf16)r2.w, (__bf16)r3.w};
    *(bf16x4*)&tileT[(nc + 0) * 72 + kr] = c0;
    *(bf16x4*)&tileT[(nc + 1) * 72 + kr] = c1;
    *(bf16x4*)&tileT[(nc + 2) * 72 + kr] = c2;
    *(bf16x4*)&tileT[(nc + 3) * 72 + kr] = c3;
    __syncthreads();
#pragma unroll
    for (int i = 0; i < 2; ++i) {
        int p = i * 256 + tid;
        int n = p >> 3, kg = p & 7;
        bf16x8 v = *(const bf16x8*)&tileT[n * 72 + kg * 8];
        *(bf16x8*)(dst + (size_t)(nb + n) * K + kb + kg * 8) = v;
    }
}

// ---------------- gate+up GEMM: 128x64 tile, 3 blocks/CU ---------------------
__global__ __launch_bounds__(256, 3) void gateup3_kernel(
    const __bf16* __restrict__ Xb, const __bf16* __restrict__ Wgt,
    const __bf16* __restrict__ Wut, const float* __restrict__ bg,
    const float* __restrict__ bu, const int* __restrict__ cnt,
    const int* __restrict__ list, __bf16* __restrict__ H, int T)
{
    const int e  = blockIdx.z;
    const int m0 = blockIdx.y * 128;
    const int n0 = blockIdx.x * 64;
    const int count = cnt[e];
    if (m0 >= count) return;

    __shared__ __bf16 ldsA[4096];    // 128 x 32
    __shared__ __bf16 ldsBg[2048];   // 64 x 32
    __shared__ __bf16 ldsBu[2048];
    __shared__ int s_entry[128];

    const int tid = threadIdx.x;
    if (tid < 128) {
        int r = m0 + tid;
        s_entry[tid] = (r < count) ? list[e * T + r] : list[e * T];
    }
    __syncthreads();

    // staging sources: granule p -> row=p>>2, slot j=p&3, src granule g=j^((row>>2)&3)
    const int row0 = tid >> 2, j0 = tid & 3;
    const int g0 = j0 ^ ((row0 >> 2) & 3);
    const int p1 = 256 + tid, row1 = p1 >> 2, j1 = p1 & 3;
    const int g1 = j1 ^ ((row1 >> 2) & 3);
    const __bf16* asrc0 = Xb + (size_t)(s_entry[row0] >> 1) * D_MODEL + g0 * 8;
    const __bf16* asrc1 = Xb + (size_t)(s_entry[row1] >> 1) * D_MODEL + g1 * 8;
    const __bf16* gsrc  = Wgt + ((size_t)e * D_FF + n0 + row0) * D_MODEL + g0 * 8;
    const __bf16* usrc  = Wut + ((size_t)e * D_FF + n0 + row0) * D_MODEL + g0 * 8;
    char* adst0 = (char*)ldsA + tid * 16;
    char* adst1 = (char*)ldsA + (256 + tid) * 16;
    char* gdst  = (char*)ldsBg + tid * 16;
    char* udst  = (char*)ldsBu + tid * 16;

    const int wv = tid >> 6, lane = tid & 63;
    const int wm = wv >> 1, wn = wv & 1;
    const int q = lane >> 4, ln = lane & 15;
    int aoff[4], boff[2];
#pragma unroll
    for (int i = 0; i < 4; ++i) aoff[i] = frag_off(wm * 64 + i * 16 + ln, q);
#pragma unroll
    for (int i = 0; i < 2; ++i) boff[i] = frag_off(wn * 32 + i * 16 + ln, q);

    floatx4 accg[4][2] = {};
    floatx4 accu[4][2] = {};

    for (int k0 = 0; k0 < D_MODEL; k0 += 32) {
        gload16(asrc0 + k0, adst0);
        gload16(asrc1 + k0, adst1);
        gload16(gsrc + k0, gdst);
        gload16(usrc + k0, udst);
        __syncthreads();

        bf16x8 af[4], bgf[2], buf[2];
#pragma unroll
        for (int i = 0; i < 4; ++i) af[i]  = *(const bf16x8*)&ldsA[aoff[i]];
#pragma unroll
        for (int i = 0; i < 2; ++i) bgf[i] = *(const bf16x8*)&ldsBg[boff[i]];
#pragma unroll
        for (int i = 0; i < 2; ++i) buf[i] = *(const bf16x8*)&ldsBu[boff[i]];
#pragma unroll
        for (int mi = 0; mi < 4; ++mi)
#pragma unroll
            for (int ni = 0; ni < 2; ++ni) {
                accg[mi][ni] = __builtin_amdgcn_mfma_f32_16x16x32_bf16(af[mi], bgf[ni], accg[mi][ni], 0, 0, 0);
                accu[mi][ni] = __builtin_amdgcn_mfma_f32_16x16x32_bf16(af[mi], buf[ni], accu[mi][ni], 0, 0, 0);
            }
        __syncthreads();
    }

#pragma unroll
    for (int ni = 0; ni < 2; ++ni) {
        int col = n0 + wn * 32 + ni * 16 + ln;
        float bgv = bg[e * D_FF + col];
        float buv = bu[e * D_FF + col];
#pragma unroll
        for (int mi = 0; mi < 4; ++mi) {
            int lrow0 = wm * 64 + mi * 16 + q * 4;
#pragma unroll
            for (int r = 0; r < 4; ++r) {
                int lr = lrow0 + r;
                if (m0 + lr < count) {
                    int entry = s_entry[lr];
                    float g = accg[mi][ni][r] + bgv;
                    float u = accu[mi][ni][r] + buv;
                    float h = g / (1.f + __expf(-g)) * u;
                    H[(size_t)entry * D_FF + col] = (__bf16)h;
                }
            }
        }
    }
}

// ---------------- down GEMM: 128x128, K-split x4, plain stores to Y ----------
__global__ __launch_bounds__(256, 3) void down3_kernel(
    const __bf16* __restrict__ H, const __bf16* __restrict__ Wdt,
    const float* __restrict__ bd, const int* __restrict__ cnt,
    const int* __restrict__ list, float* __restrict__ Y, int T)
{
    const int e  = blockIdx.z >> 2;
    const int kc = blockIdx.z & 3;
    const int m0 = blockIdx.y * 128;
    const int n0 = blockIdx.x * 128;
    const int count = cnt[e];
    if (m0 >= count) return;

    __shared__ __bf16 ldsA[4096];
    __shared__ __bf16 ldsB[4096];
    __shared__ int s_entry[128];

    const int tid = threadIdx.x;
    if (tid < 128) {
        int r = m0 + tid;
        s_entry[tid] = (r < count) ? list[e * T + r] : list[e * T];
    }
    __syncthreads();

    const int kbase = kc * (D_FF / 4);
    const __bf16* asrc[2]; const __bf16* bsrc[2];
    char* adst[2]; char* bdst[2];
#pragma unroll
    for (int i = 0; i < 2; ++i) {
        int p = i * 256 + tid;
        int row = p >> 2, j = p & 3;
        int g = j ^ ((row >> 2) & 3);
        asrc[i] = H + (size_t)s_entry[row] * D_FF + kbase + g * 8;
        bsrc[i] = Wdt + ((size_t)e * D_MODEL + n0 + row) * D_FF + kbase + g * 8;
        adst[i] = (char*)ldsA + (size_t)p * 16;
        bdst[i] = (char*)ldsB + (size_t)p * 16;
    }

    const int wv = tid >> 6, lane = tid & 63;
    const int wm = wv >> 1, wn = wv & 1;
    const int q = lane >> 4, ln = lane & 15;
    int aoff[4], boff[4];
#pragma unroll
    for (int i = 0; i < 4; ++i) {
        aoff[i] = frag_off(wm * 64 + i * 16 + ln, q);
        boff[i] = frag_off(wn * 64 + i * 16 + ln, q);
    }

    floatx4 acc[4][4] = {};

    for (int k0 = 0; k0 < D_FF / 4; k0 += 32) {
#pragma unroll
        for (int i = 0; i < 2; ++i) {
            gload16(asrc[i] + k0, adst[i]);
            gload16(bsrc[i] + k0, bdst[i]);
        }
        __syncthreads();

        bf16x8 af[4], bf[4];
#pragma unroll
        for (int i = 0; i < 4; ++i) af[i] = *(const bf16x8*)&ldsA[aoff[i]];
#pragma unroll
        for (int i = 0; i < 4; ++i) bf[i] = *(const bf16x8*)&ldsB[boff[i]];
#pragma unroll
        for (int mi = 0; mi < 4; ++mi)
#pragma unroll
            for (int ni = 0; ni < 4; ++ni)
                acc[mi][ni] = __builtin_amdgcn_mfma_f32_16x16x32_bf16(af[mi], bf[ni], acc[mi][ni], 0, 0, 0);
        __syncthreads();
    }

    const size_t kc_off = (size_t)kc * 2 * T * D_MODEL;
#pragma unroll
    for (int ni = 0; ni < 4; ++ni) {
        int col = n0 + wn * 64 + ni * 16 + ln;
        float bdv = (kc == 0) ? bd[e * D_MODEL + col] : 0.f;
#pragma unroll
        for (int mi = 0; mi < 4; ++mi) {
            int lrow0 = wm * 64 + mi * 16 + q * 4;
#pragma unroll
            for (int r = 0; r < 4; ++r) {
                int lr = lrow0 + r;
                if (m0 + lr < count) {
                    int entry = s_entry[lr];
                    Y[kc_off + (size_t)entry * D_MODEL + col] = acc[mi][ni][r] + bdv;
                }
            }
        }
    }
}

// ---------------- combine: out[t] = w0*sum_kc Y[kc][2t] + w1*sum_kc Y[kc][2t+1]
__global__ __launch_bounds__(256) void combine_kernel(
    const float* __restrict__ Y, const float* __restrict__ w_slot,
    float* __restrict__ out, int T)
{
    int idx = blockIdx.x * 256 + threadIdx.x;      // over T*D/4
    int t = idx >> 8;                               // D/4 = 256
    const float4* Y4 = (const float4*)Y;
    size_t r0 = (size_t)(2 * t) * 256 + (idx & 255);
    size_t r1 = r0 + 256;
    size_t ks = (size_t)2 * T * 256;
    float4 a = Y4[r0], b = Y4[r1];
#pragma unroll
    for (int kc = 1; kc < 4; ++kc) {
        float4 va = Y4[r0 + kc * ks], vb = Y4[r1 + kc * ks];
        a.x += va.x; a.y += va.y; a.z += va.z; a.w += va.w;
        b.x += vb.x; b.y += vb.y; b.z += vb.z; b.w += vb.w;
    }
    float w0 = w_slot[2 * t], w1 = w_slot[2 * t + 1];
    float4 o = {w0 * a.x + w1 * b.x, w0 * a.y + w1 * b.y,
                w0 * a.z + w1 * b.z, w0 * a.w + w1 * b.w};
    ((float4*)out)[idx] = o;
}

// ============================================================================
extern "C" void kernel_launch(void* const* d_in, const int* in_sizes, int n_in,
                              void* d_out, int out_size, void* d_ws, size_t ws_size,
                              hipStream_t stream) {
    const float* x  = (const float*)d_in[0];
    const float* Wr = (const float*)d_in[1];
    const float* br = (const float*)d_in[2];
    const float* Wg = (const float*)d_in[3];
    const float* bg = (const float*)d_in[4];
    const float* Wu = (const float*)d_in[5];
    const float* bu = (const float*)d_in[6];
    const float* Wd = (const float*)d_in[7];
    const float* bd = (const float*)d_in[8];
    float* out = (float*)d_out;
    const int T = in_sizes[0] / D_MODEL;   // 2048

    char* ws = (char*)d_ws;
    size_t off = 256;
    int*   cnt    = (int*)ws;
    int*   list   = (int*)(ws + off);              off += (size_t)NE * T * 4;
    float* w_slot = (float*)(ws + off);            off += (size_t)2 * T * 4;
    off = (off + 1023) & ~(size_t)1023;
    __bf16* Xb  = (__bf16*)(ws + off);             off += (size_t)T * D_MODEL * 2;
    __bf16* H   = (__bf16*)(ws + off);             off += (size_t)2 * T * D_FF * 2;
    __bf16* Wgt = (__bf16*)(ws + off);
    float*  Y   = (float*)(ws + off);              // aliases Wgt (dead after gateup)
    off += (size_t)NE * D_MODEL * D_FF * 2;        // 67.1 MB >= Y's 64 MB
    __bf16* Wut = (__bf16*)(ws + off);             off += (size_t)NE * D_MODEL * D_FF * 2;
    __bf16* Wdt = (__bf16*)(ws + off);             off += (size_t)NE * D_FF * D_MODEL * 2;

    hipMemsetAsync(cnt, 0, 256, stream);

    router_kernel<<<dim3((T + 3) / 4), dim3(256), 0, stream>>>(x, Wr, br, cnt, list, w_slot, T);

    prep_kernel<<<dim3(25600), dim3(256), 0, stream>>>(Wg, Wu, Wd, x, Wgt, Wut, Wdt, Xb);

    dim3 gb(D_FF / 64, (T + 127) / 128, NE);
    gateup3_kernel<<<gb, dim3(256), 0, stream>>>(Xb, Wgt, Wut, bg, bu, cnt, list, H, T);

    dim3 gc(D_MODEL / 128, (T + 127) / 128, NE * 4);
    down3_kernel<<<gc, dim3(256), 0, stream>>>(H, Wdt, bd, cnt, list, Y, T);

    combine_kernel<<<dim3(T * D_MODEL / 4 / 256), dim3(256), 0, stream>>>(Y, w_slot, out, T);
}